// Round 11
// baseline (326.481 us; speedup 1.0000x reference)
//
#include <hip/hip_runtime.h>
#include <float.h>
#include <math.h>

#define B_  8
#define H_  8
#define L_  2048
#define D_  64
#define NS  40          // num selected = min(5*ceil(ln(2048)), 2048) = 40
#define BH  (B_*H_)
#define SCALE 0.125f    // d^-0.5

// XCD swizzle: MI355X dispatches block b to XCD (b % 8).  We remap so that
// bh % 8 == b % 8 for every kernel -> all blocks of one bh run on one XCD,
// keeping that bh's k/v/measure/attn slices resident in its 4MB L2.

// DPP helper: x += lane_shifted_down_by<SHR>(x), within rows of 16 lanes,
// out-of-row reads return 0 (bound_ctrl).  Pure VALU - no LDS pipe.
template<int CTRL>
__device__ __forceinline__ float dpp_add(float x) {
    int s = __builtin_amdgcn_update_dpp(0, __float_as_int(x), CTRL, 0xF, 0xF, true);
    return x + __int_as_float(s);
}

// ---------------------------------------------------------------------------
// K1: measure + cumsum, GRID-FUSED (independent dataflow; cumsum rides in
// measure's memory slack).  measure: one wave/query, octet gather + DPP dot;
// bound by L2 scattered-line throughput (~79us floor, see R7 post-mortem).
// cumsum (blocks 0..255): bh x 4 column-groups, stripe prefix scheme.
// ---------------------------------------------------------------------------
__global__ __launch_bounds__(256) void measure_cumsum_kernel(
    const float* __restrict__ q, const float* __restrict__ k,
    const int* __restrict__ ridx, float* __restrict__ measure,
    const float* __restrict__ v, float* __restrict__ out)
{
    __shared__ float4 part[64][5];        // cumsum only; 5.1KB
    if (blockIdx.x < 256) {
        // ---------------- cumsum ----------------
        int b = blockIdx.x;
        int xcd = b & 7, s = b >> 3;          // s in 0..31
        int bh  = xcd + ((s >> 2) << 3);      // 8 bh per XCD
        int cg  = s & 3;
        int col = threadIdx.x & 3, sub = threadIdx.x >> 2;   // sub 0..63
        int c0 = cg*4 + col;
        int r0 = sub * 32;
        const float4* vb = (const float4*)(v + (size_t)bh * L_ * D_);
        float4*       ob = (float4*)(out + (size_t)bh * L_ * D_);

        float4 acc = make_float4(0,0,0,0);
        #pragma unroll
        for (int r = 0; r < 32; ++r) {
            float4 x = vb[(size_t)(r0 + r)*16 + c0];
            acc.x += x.x; acc.y += x.y; acc.z += x.z; acc.w += x.w;
        }
        part[sub][col] = acc;
        __syncthreads();

        float4 run = make_float4(0,0,0,0);
        for (int cc = 0; cc < sub; ++cc) {
            float4 x = part[cc][col];
            run.x += x.x; run.y += x.y; run.z += x.z; run.w += x.w;
        }

        #pragma unroll
        for (int r = 0; r < 32; ++r) {
            float4 x = vb[(size_t)(r0 + r)*16 + c0];
            run.x += x.x; run.y += x.y; run.z += x.z; run.w += x.w;
            ob[(size_t)(r0 + r)*16 + c0] = run;
        }
        return;
    }
    // ---------------- measure ----------------
    int wave = threadIdx.x >> 6, lane = threadIdx.x & 63;
    int b = blockIdx.x - 256;                 // 256 = 0 mod 8: swizzle kept
    int xcd = b & 7, s = b >> 3;              // s in 0..4095
    int bh  = xcd + ((s >> 9) << 3);
    int i   = (s & 511) * 4 + wave;
    int oct = lane >> 3;
    int e   = lane & 7;

    int4 r4 = *(const int4*)(ridx + i * NS + oct * 4);
    int  r5 = ridx[i * NS + 32 + oct];
    int rr[5] = { r4.x, r4.y, r4.z, r4.w, r5 };

    const float4* kb = (const float4*)(k + (size_t)bh * L_ * D_);
    const float4* qp = (const float4*)(q + ((size_t)bh * L_ + i) * D_);
    float4 qa = qp[e];
    float4 qb = qp[e + 8];

    float mx = -FLT_MAX, sm = 0.f;
    #pragma unroll
    for (int p = 0; p < 5; ++p) {
        int base = rr[p] << 4;
        float4 ka = kb[base + e];
        float4 kc = kb[base + 8 + e];
        float pa = qa.x*ka.x + qa.y*ka.y + qa.z*ka.z + qa.w*ka.w;
        float pb = qb.x*kc.x + qb.y*kc.y + qb.z*kc.z + qb.w*kc.w;
        float pp = pa + pb;
        pp = dpp_add<0x111>(pp);
        pp = dpp_add<0x112>(pp);
        pp = dpp_add<0x114>(pp);             // holder = lane 8o+7
        mx = fmaxf(mx, pp);
        sm += pp;
    }
    mx = fmaxf(mx, __shfl_xor(mx,  8, 64));  sm += __shfl_xor(sm,  8, 64);
    mx = fmaxf(mx, __shfl_xor(mx, 16, 64));  sm += __shfl_xor(sm, 16, 64);
    mx = fmaxf(mx, __shfl_xor(mx, 32, 64));  sm += __shfl_xor(sm, 32, 64);
    if (lane == 7)
        measure[(size_t)bh * L_ + i] = mx - sm * (1.0f / (float)L_);
}

// ---------------------------------------------------------------------------
// K2: top-NS per (b,h), segmented tournament.  Output SORTED BY QROW
// (ascending), packed (origRank<<16)|qrow, so consumer groups of 4 get small
// group-max(qrow) early -> causal work-skip.  Selection identical to
// lax.top_k (value desc, index asc).
// ---------------------------------------------------------------------------
__global__ __launch_bounds__(256) void topk_kernel(
    const float* __restrict__ measure, int* __restrict__ idxOut)
{
    __shared__ float segVal[4][NS];
    __shared__ int   segIdx[4][NS];
    int bh = blockIdx.x;
    int t = threadIdx.x, w = t >> 6, lane = t & 63;
    const float4* m4 = (const float4*)(measure + (size_t)bh * L_);

    float vals[8];
    float4 a  = m4[128*w + 2*lane];
    float4 bb = m4[128*w + 2*lane + 1];
    vals[0]=a.x;  vals[1]=a.y;  vals[2]=a.z;  vals[3]=a.w;
    vals[4]=bb.x; vals[5]=bb.y; vals[6]=bb.z; vals[7]=bb.w;
    int gbase = 512*w + 8*lane;

    float lv = -FLT_MAX; int li = 0x7fffffff;
    #pragma unroll
    for (int e = 0; e < 8; ++e)
        if (vals[e] > lv) { lv = vals[e]; li = gbase + e; }

    for (int r = 0; r < NS; ++r) {
        float v = lv; int idx = li;
        #pragma unroll
        for (int off = 32; off; off >>= 1) {
            float ov = __shfl_xor(v, off, 64);
            int   oi = __shfl_xor(idx, off, 64);
            if (ov > v || (ov == v && oi < idx)) { v = ov; idx = oi; }
        }
        if (lane == 0) { segVal[w][r] = v; segIdx[w][r] = idx; }
        if (((idx >> 3) & 63) == lane) {
            int slot = idx & 7;
            #pragma unroll
            for (int e = 0; e < 8; ++e) if (e == slot) vals[e] = -FLT_MAX;
            lv = -FLT_MAX; li = 0x7fffffff;
            #pragma unroll
            for (int e = 0; e < 8; ++e)
                if (vals[e] > lv) { lv = vals[e]; li = gbase + e; }
        }
    }
    __syncthreads();

    if (w == 0) {
        int s = lane & 3;
        int h = 0;
        float hv = segVal[s][0]; int hi_ = segIdx[s][0];
        int myQrow = 0x7fffffff;             // lane r captures rank-r winner
        for (int r = 0; r < NS; ++r) {
            float v = hv; int idx = hi_; int ws = s;
            float ov = __shfl_xor(v, 1, 64); int oi = __shfl_xor(idx, 1, 64); int os = __shfl_xor(ws, 1, 64);
            if (ov > v || (ov == v && oi < idx)) { v = ov; idx = oi; ws = os; }
            ov = __shfl_xor(v, 2, 64); oi = __shfl_xor(idx, 2, 64); os = __shfl_xor(ws, 2, 64);
            if (ov > v || (ov == v && oi < idx)) { v = ov; idx = oi; ws = os; }
            if (lane == r) myQrow = idx;     // all lanes hold winner post-butterfly
            if (s == ws) {
                ++h;
                if (h < NS) { hv = segVal[s][h]; hi_ = segIdx[s][h]; }
                else        { hv = -FLT_MAX;     hi_ = 0x7fffffff;  }
            }
        }
        // sort the 40 winners by qrow (ascending; qrows are distinct)
        int pos = 0;
        for (int j = 0; j < NS; ++j) {
            int qj = __shfl(myQrow, j, 64);
            if (lane < NS && qj < myQrow) ++pos;
        }
        if (lane >= NS) pos = lane;          // park inactive lanes, no collision
        int packed = (lane << 16) | (myQrow & 0xffff);   // origRank<<16 | qrow
        int sorted = __builtin_amdgcn_ds_permute(pos << 2, packed);  // push to pos
        if (lane < NS) idxOut[bh*NS + lane] = sorted;
    }
}

// ---------------------------------------------------------------------------
// K4a: scores + softmax.  Block = (bh, group of 4 SORTED-by-qrow entries).
// R11 FIX: the chunk loop is again FULLY UNROLLED (static c) with the skip
// as a block-uniform `if (c < cmax)` INSIDE the unroll.  R10's dynamic
// `for c < cmax` made sc0/sc1 runtime-indexed -> scratch spill (rule #20),
// which ate the entire ~46% work-skip.  Static c keeps them in registers;
// block-uniform guard keeps the interior barriers legal; skipped chunks
// leave sc=0 so attn still gets exact zeros past qrow.
// ---------------------------------------------------------------------------
__global__ __launch_bounds__(256) void scores_kernel(
    const float* __restrict__ q, const float* __restrict__ k,
    const int* __restrict__ idxSel, float* __restrict__ attn)
{
    __shared__ float4 kbuf[16 * 129];   // [g][j], stride 129 f4
    __shared__ int qpk[4];
    int b = blockIdx.x;
    int xcd = b & 7, s = b >> 3;          // s in 0..79
    int bh  = xcd + ((s / 10) << 3);
    int grp = s % 10;
    int qi = threadIdx.x >> 6, sub = threadIdx.x & 63;
    int packed = idxSel[bh*NS + grp*4 + qi];
    int qrow = packed & 0xffff;
    int rank = packed >> 16;

    if (sub == 0) qpk[qi] = qrow;
    __syncthreads();
    int maxq = max(max(qpk[0], qpk[1]), max(qpk[2], qpk[3]));
    int cmax = (maxq >> 7) + 1;           // block-uniform -> barrier-legal

    const float4* qrp = (const float4*)(q + ((size_t)bh * L_ + qrow) * D_);
    float4 qreg[16];
    #pragma unroll
    for (int g = 0; g < 16; ++g) qreg[g] = qrp[g];    // wave-uniform

    const float4* kb = (const float4*)(k + (size_t)bh * L_ * D_);
    float sc0[16], sc1[16];
    #pragma unroll
    for (int c = 0; c < 16; ++c) { sc0[c] = 0.f; sc1[c] = 0.f; }

    #pragma unroll
    for (int c = 0; c < 16; ++c) {
        if (c < cmax) {                                // block-uniform skip
            __syncthreads();                           // kbuf reuse guard
            int j0 = c * 128;
            #pragma unroll
            for (int it = 0; it < 8; ++it) {           // coalesced stage
                int fi = threadIdx.x + 256*it;
                int g = fi & 15, j = fi >> 4;
                kbuf[g*129 + j] = kb[(size_t)(j0 + j)*16 + g];
            }
            __syncthreads();
            float acc0 = 0.f, acc1 = 0.f;
            #pragma unroll
            for (int g = 0; g < 16; ++g) {
                float4 k0 = kbuf[g*129 + sub];         // dense b128
                float4 k1 = kbuf[g*129 + sub + 64];
                float4 qq = qreg[g];
                acc0 += qq.x*k0.x + qq.y*k0.y + qq.z*k0.z + qq.w*k0.w;
                acc1 += qq.x*k1.x + qq.y*k1.y + qq.z*k1.z + qq.w*k1.w;
            }
            sc0[c] = acc0 * SCALE;                     // static idx: registers
            sc1[c] = acc1 * SCALE;
        }
    }

    // masked softmax, wave-local (guards false for skipped chunks: sc stays 0)
    float mx = -FLT_MAX;
    #pragma unroll
    for (int c = 0; c < 16; ++c) {
        if (c*128 + sub      <= qrow) mx = fmaxf(mx, sc0[c]);
        if (c*128 + sub + 64 <= qrow) mx = fmaxf(mx, sc1[c]);
    }
    #pragma unroll
    for (int off = 32; off; off >>= 1) mx = fmaxf(mx, __shfl_xor(mx, off, 64));

    float sum = 0.f;
    #pragma unroll
    for (int c = 0; c < 16; ++c) {
        sc0[c] = (c*128 + sub      <= qrow) ? __expf(sc0[c] - mx) : 0.f;
        sc1[c] = (c*128 + sub + 64 <= qrow) ? __expf(sc1[c] - mx) : 0.f;
        sum += sc0[c] + sc1[c];
    }
    #pragma unroll
    for (int off = 32; off; off >>= 1) sum += __shfl_xor(sum, off, 64);
    float inv = 1.f / sum;

    float* arow = attn + (size_t)(bh*NS + rank) * L_;
    #pragma unroll
    for (int c = 0; c < 16; ++c) {
        arow[c*128 + sub]      = sc0[c] * inv;         // coalesced; 0 past qrow
        arow[c*128 + sub + 64] = sc1[c] * inv;
    }
}

// ---------------------------------------------------------------------------
// K4b: out[bh, qrow_r, :] = attn_row_r @ v for 4 sorted entries per block.
// Sorted grouping tightens maxq -> the jhi bound skips ~46% of v reads/FMAs
// across groups.  attn staged by ORIGINAL rank (packed>>16).
// ---------------------------------------------------------------------------
__global__ __launch_bounds__(256) void pv_kernel(
    const float* __restrict__ v, const int* __restrict__ idxSel,
    const float* __restrict__ attn, float* __restrict__ out)
{
    __shared__ float wl[4][L_ + 64];    // per-rank weights, j + 4*(j>>7) pad
    __shared__ float4 part[16][16];
    __shared__ int qr4[4];
    __shared__ int rk4[4];
    int b = blockIdx.x;
    int xcd = b & 7, s = b >> 3;          // s in 0..79
    int bh  = xcd + ((s / 10) << 3);
    int grp = s % 10;
    int t = threadIdx.x;
    if (t < 4) {
        int p = idxSel[bh*NS + grp*4 + t];
        qr4[t] = p & 0xffff;
        rk4[t] = p >> 16;
    }
    __syncthreads();                    // rk4 needed by the staging loop

    // stage 4 weight rows (coalesced f4 loads)
    #pragma unroll
    for (int it = 0; it < 8; ++it) {
        int f = t + 256*it;             // 0..2047 f4 across 4 rows
        int rr = f >> 9, fi = f & 511;
        const float4* ar = (const float4*)(attn + (size_t)(bh*NS + rk4[rr]) * L_);
        float4 x = ar[fi];
        int j = 4*fi;
        *((float4*)&wl[rr][j + 4*(j >> 7)]) = x;
    }
    __syncthreads();

    int maxq = max(max(qr4[0], qr4[1]), max(qr4[2], qr4[3]));
    int d4 = t & 15, seg = t >> 4;
    const float4* vb = (const float4*)(v + (size_t)bh * L_ * D_);
    float4 acc[4];
    #pragma unroll
    for (int rr = 0; rr < 4; ++rr) acc[rr] = make_float4(0,0,0,0);

    int jlo = seg*128, jhi = min(jlo + 127, maxq);
    for (int j = jlo; j <= jhi; ++j) {
        float4 x = vb[(size_t)j*16 + d4];          // read once
        int jp = j + 4*(j >> 7);
        #pragma unroll
        for (int rr = 0; rr < 4; ++rr) {
            float wgt = wl[rr][jp];                // 2-way conflict (free)
            acc[rr].x += wgt*x.x; acc[rr].y += wgt*x.y;
            acc[rr].z += wgt*x.z; acc[rr].w += wgt*x.w;
        }
    }

    #pragma unroll
    for (int rr = 0; rr < 4; ++rr) {
        part[seg][d4] = acc[rr];
        __syncthreads();
        float4 a = acc[rr];
        for (int s2 = 8; s2; s2 >>= 1) {
            if (seg < s2) {
                float4 o = part[seg + s2][d4];
                a.x += o.x; a.y += o.y; a.z += o.z; a.w += o.w;
                part[seg][d4] = a;
            }
            __syncthreads();
        }
        if (seg == 0) {
            float4* orow = (float4*)(out + ((size_t)bh * L_ + qr4[rr]) * D_);
            orow[d4] = a;
        }
        __syncthreads();                // before part reuse
    }
}

// ---------------------------------------------------------------------------
extern "C" void kernel_launch(void* const* d_in, const int* in_sizes, int n_in,
                              void* d_out, int out_size, void* d_ws, size_t ws_size,
                              hipStream_t stream) {
    const float* q    = (const float*)d_in[0];
    const float* k    = (const float*)d_in[1];
    const float* v    = (const float*)d_in[2];
    const int*   ridx = (const int*)d_in[3];

    float* out     = (float*)d_out;                    // (B,H,L,D)
    float* attnOut = out + (size_t)BH * L_ * D_;       // (B,H,NS,L)

    float*  measure = (float*)d_ws;                                          // BH*L floats
    int*    idxSel  = (int*)((char*)d_ws + (size_t)BH * L_ * sizeof(float)); // BH*NS ints

    measure_cumsum_kernel<<<256 + BH * L_ / 4, 256, 0, stream>>>(
        q, k, ridx, measure, v, out);
    topk_kernel   <<<BH,          256, 0, stream>>>(measure, idxSel);
    scores_kernel <<<BH * 10,     256, 0, stream>>>(q, k, idxSel, attnOut);
    pv_kernel     <<<BH * 10,     256, 0, stream>>>(v, idxSel, attnOut, out);
}

// Round 12
// 320.584 us; speedup vs baseline: 1.0184x; 1.0184x over previous
//
#include <hip/hip_runtime.h>
#include <float.h>
#include <math.h>

#define B_  8
#define H_  8
#define L_  2048
#define D_  64
#define NS  40          // num selected = min(5*ceil(ln(2048)), 2048) = 40
#define BH  (B_*H_)
#define SCALE 0.125f    // d^-0.5

// XCD swizzle: MI355X dispatches block b to XCD (b % 8).  We remap so that
// bh % 8 == b % 8 for every kernel -> all blocks of one bh run on one XCD,
// keeping that bh's k/v/measure/attn slices resident in its 4MB L2.

// DPP helper: x += lane_shifted_down_by<SHR>(x), within rows of 16 lanes,
// out-of-row reads return 0 (bound_ctrl).  Pure VALU - no LDS pipe.
template<int CTRL>
__device__ __forceinline__ float dpp_add(float x) {
    int s = __builtin_amdgcn_update_dpp(0, __float_as_int(x), CTRL, 0xF, 0xF, true);
    return x + __int_as_float(s);
}

// ---------------------------------------------------------------------------
// K1: measure + cumsum, GRID-FUSED (independent dataflow; cumsum rides in
// measure's memory slack).  measure: one wave/query, octet gather + DPP dot;
// bound by L2 scattered-line throughput (~79us floor; 1.34GB of random 64B
// lines at ~17 TB/s effective.  R7's LDS-tiling attempt was 3.4x worse).
// cumsum (blocks 0..255): bh x 4 column-groups, stripe prefix scheme.
// This exact configuration measured 322.4us (R9) - session best.
// ---------------------------------------------------------------------------
__global__ __launch_bounds__(256) void measure_cumsum_kernel(
    const float* __restrict__ q, const float* __restrict__ k,
    const int* __restrict__ ridx, float* __restrict__ measure,
    const float* __restrict__ v, float* __restrict__ out)
{
    __shared__ float4 part[64][5];        // cumsum only; 5.1KB
    if (blockIdx.x < 256) {
        // ---------------- cumsum ----------------
        int b = blockIdx.x;
        int xcd = b & 7, s = b >> 3;          // s in 0..31
        int bh  = xcd + ((s >> 2) << 3);      // 8 bh per XCD
        int cg  = s & 3;
        int col = threadIdx.x & 3, sub = threadIdx.x >> 2;   // sub 0..63
        int c0 = cg*4 + col;
        int r0 = sub * 32;
        const float4* vb = (const float4*)(v + (size_t)bh * L_ * D_);
        float4*       ob = (float4*)(out + (size_t)bh * L_ * D_);

        float4 acc = make_float4(0,0,0,0);
        #pragma unroll
        for (int r = 0; r < 32; ++r) {
            float4 x = vb[(size_t)(r0 + r)*16 + c0];
            acc.x += x.x; acc.y += x.y; acc.z += x.z; acc.w += x.w;
        }
        part[sub][col] = acc;
        __syncthreads();

        float4 run = make_float4(0,0,0,0);
        for (int cc = 0; cc < sub; ++cc) {
            float4 x = part[cc][col];
            run.x += x.x; run.y += x.y; run.z += x.z; run.w += x.w;
        }

        #pragma unroll
        for (int r = 0; r < 32; ++r) {
            float4 x = vb[(size_t)(r0 + r)*16 + c0];
            run.x += x.x; run.y += x.y; run.z += x.z; run.w += x.w;
            ob[(size_t)(r0 + r)*16 + c0] = run;
        }
        return;
    }
    // ---------------- measure ----------------
    int wave = threadIdx.x >> 6, lane = threadIdx.x & 63;
    int b = blockIdx.x - 256;                 // 256 = 0 mod 8: swizzle kept
    int xcd = b & 7, s = b >> 3;              // s in 0..4095
    int bh  = xcd + ((s >> 9) << 3);
    int i   = (s & 511) * 4 + wave;
    int oct = lane >> 3;
    int e   = lane & 7;

    int4 r4 = *(const int4*)(ridx + i * NS + oct * 4);
    int  r5 = ridx[i * NS + 32 + oct];
    int rr[5] = { r4.x, r4.y, r4.z, r4.w, r5 };

    const float4* kb = (const float4*)(k + (size_t)bh * L_ * D_);
    const float4* qp = (const float4*)(q + ((size_t)bh * L_ + i) * D_);
    float4 qa = qp[e];
    float4 qb = qp[e + 8];

    float mx = -FLT_MAX, sm = 0.f;
    #pragma unroll
    for (int p = 0; p < 5; ++p) {
        int base = rr[p] << 4;
        float4 ka = kb[base + e];
        float4 kc = kb[base + 8 + e];
        float pa = qa.x*ka.x + qa.y*ka.y + qa.z*ka.z + qa.w*ka.w;
        float pb = qb.x*kc.x + qb.y*kc.y + qb.z*kc.z + qb.w*kc.w;
        float pp = pa + pb;
        pp = dpp_add<0x111>(pp);
        pp = dpp_add<0x112>(pp);
        pp = dpp_add<0x114>(pp);             // holder = lane 8o+7
        mx = fmaxf(mx, pp);
        sm += pp;
    }
    mx = fmaxf(mx, __shfl_xor(mx,  8, 64));  sm += __shfl_xor(sm,  8, 64);
    mx = fmaxf(mx, __shfl_xor(mx, 16, 64));  sm += __shfl_xor(sm, 16, 64);
    mx = fmaxf(mx, __shfl_xor(mx, 32, 64));  sm += __shfl_xor(sm, 32, 64);
    if (lane == 7)
        measure[(size_t)bh * L_ + i] = mx - sm * (1.0f / (float)L_);
}

// ---------------------------------------------------------------------------
// K2: top-NS per (b,h), segmented tournament (R9 form: rank-ordered output,
// no qrow sort - the sorted-group work-skip was null twice, R10/R11).
// Each wave extracts its 512-row segment's sorted top-40 in-wave (zero
// barriers), one barrier, wave 0 merges the 4 sorted lists.
// Comparator: (value desc, index asc) == lax.top_k tie rule.
// ---------------------------------------------------------------------------
__global__ __launch_bounds__(256) void topk_kernel(
    const float* __restrict__ measure, int* __restrict__ idxOut)
{
    __shared__ float segVal[4][NS];
    __shared__ int   segIdx[4][NS];
    int bh = blockIdx.x;
    int t = threadIdx.x, w = t >> 6, lane = t & 63;
    const float4* m4 = (const float4*)(measure + (size_t)bh * L_);

    float vals[8];
    float4 a  = m4[128*w + 2*lane];
    float4 bb = m4[128*w + 2*lane + 1];
    vals[0]=a.x;  vals[1]=a.y;  vals[2]=a.z;  vals[3]=a.w;
    vals[4]=bb.x; vals[5]=bb.y; vals[6]=bb.z; vals[7]=bb.w;
    int gbase = 512*w + 8*lane;

    float lv = -FLT_MAX; int li = 0x7fffffff;
    #pragma unroll
    for (int e = 0; e < 8; ++e)
        if (vals[e] > lv) { lv = vals[e]; li = gbase + e; }

    for (int r = 0; r < NS; ++r) {
        float v = lv; int idx = li;
        #pragma unroll
        for (int off = 32; off; off >>= 1) {
            float ov = __shfl_xor(v, off, 64);
            int   oi = __shfl_xor(idx, off, 64);
            if (ov > v || (ov == v && oi < idx)) { v = ov; idx = oi; }
        }
        if (lane == 0) { segVal[w][r] = v; segIdx[w][r] = idx; }
        if (((idx >> 3) & 63) == lane) {
            int slot = idx & 7;
            #pragma unroll
            for (int e = 0; e < 8; ++e) if (e == slot) vals[e] = -FLT_MAX;
            lv = -FLT_MAX; li = 0x7fffffff;
            #pragma unroll
            for (int e = 0; e < 8; ++e)
                if (vals[e] > lv) { lv = vals[e]; li = gbase + e; }
        }
    }
    __syncthreads();

    if (w == 0) {
        int s = lane & 3;
        int h = 0;
        float hv = segVal[s][0]; int hi_ = segIdx[s][0];
        for (int r = 0; r < NS; ++r) {
            float v = hv; int idx = hi_; int ws = s;
            float ov = __shfl_xor(v, 1, 64); int oi = __shfl_xor(idx, 1, 64); int os = __shfl_xor(ws, 1, 64);
            if (ov > v || (ov == v && oi < idx)) { v = ov; idx = oi; ws = os; }
            ov = __shfl_xor(v, 2, 64); oi = __shfl_xor(idx, 2, 64); os = __shfl_xor(ws, 2, 64);
            if (ov > v || (ov == v && oi < idx)) { v = ov; idx = oi; ws = os; }
            if (lane == 0) idxOut[bh*NS + r] = idx;
            if (s == ws) {
                ++h;
                if (h < NS) { hv = segVal[s][h]; hi_ = segIdx[s][h]; }
                else        { hv = -FLT_MAX;     hi_ = 0x7fffffff;  }
            }
        }
    }
}

// ---------------------------------------------------------------------------
// K4a: scores + softmax fused.  Block = (bh, group of 4 ranks), one wave per
// rank, XCD-swizzled (k slice L2-resident).  Writes normalized weights
// (zeros past qrow).  (R9/R6 form.)
// ---------------------------------------------------------------------------
__global__ __launch_bounds__(256) void scores_kernel(
    const float* __restrict__ q, const float* __restrict__ k,
    const int* __restrict__ idxSel, float* __restrict__ attn)
{
    __shared__ float4 kbuf[16 * 129];   // [g][j], stride 129 f4
    int b = blockIdx.x;
    int xcd = b & 7, s = b >> 3;          // s in 0..79
    int bh  = xcd + ((s / 10) << 3);
    int grp = s % 10;
    int qi = threadIdx.x >> 6, sub = threadIdx.x & 63;
    int rank = grp*4 + qi;
    int qrow = idxSel[bh*NS + rank];

    const float4* qrp = (const float4*)(q + ((size_t)bh * L_ + qrow) * D_);
    float4 qreg[16];
    #pragma unroll
    for (int g = 0; g < 16; ++g) qreg[g] = qrp[g];    // wave-uniform

    const float4* kb = (const float4*)(k + (size_t)bh * L_ * D_);
    float sc0[16], sc1[16];

    #pragma unroll
    for (int c = 0; c < 16; ++c) {
        __syncthreads();                               // kbuf reuse guard
        int j0 = c * 128;
        #pragma unroll
        for (int it = 0; it < 8; ++it) {               // coalesced stage
            int fi = threadIdx.x + 256*it;
            int g = fi & 15, j = fi >> 4;
            kbuf[g*129 + j] = kb[(size_t)(j0 + j)*16 + g];
        }
        __syncthreads();
        float acc0 = 0.f, acc1 = 0.f;
        #pragma unroll
        for (int g = 0; g < 16; ++g) {
            float4 k0 = kbuf[g*129 + sub];             // dense b128
            float4 k1 = kbuf[g*129 + sub + 64];
            float4 qq = qreg[g];
            acc0 += qq.x*k0.x + qq.y*k0.y + qq.z*k0.z + qq.w*k0.w;
            acc1 += qq.x*k1.x + qq.y*k1.y + qq.z*k1.z + qq.w*k1.w;
        }
        sc0[c] = acc0 * SCALE;
        sc1[c] = acc1 * SCALE;
    }

    // masked softmax, wave-local (row lives in sc0/sc1)
    float mx = -FLT_MAX;
    #pragma unroll
    for (int c = 0; c < 16; ++c) {
        if (c*128 + sub      <= qrow) mx = fmaxf(mx, sc0[c]);
        if (c*128 + sub + 64 <= qrow) mx = fmaxf(mx, sc1[c]);
    }
    #pragma unroll
    for (int off = 32; off; off >>= 1) mx = fmaxf(mx, __shfl_xor(mx, off, 64));

    float sum = 0.f;
    #pragma unroll
    for (int c = 0; c < 16; ++c) {
        sc0[c] = (c*128 + sub      <= qrow) ? __expf(sc0[c] - mx) : 0.f;
        sc1[c] = (c*128 + sub + 64 <= qrow) ? __expf(sc1[c] - mx) : 0.f;
        sum += sc0[c] + sc1[c];
    }
    #pragma unroll
    for (int off = 32; off; off >>= 1) sum += __shfl_xor(sum, off, 64);
    float inv = 1.f / sum;

    float* arow = attn + (size_t)(bh*NS + rank) * L_;
    #pragma unroll
    for (int c = 0; c < 16; ++c) {
        arow[c*128 + sub]      = sc0[c] * inv;         // coalesced
        arow[c*128 + sub + 64] = sc1[c] * inv;
    }
}

// ---------------------------------------------------------------------------
// K4b: out[bh, qrow_r, :] = attn_row_r @ v for 4 ranks per block,
// XCD-swizzled (v + attn slices L2-resident).  (R9/R6 form.)
// ---------------------------------------------------------------------------
__global__ __launch_bounds__(256) void pv_kernel(
    const float* __restrict__ v, const int* __restrict__ idxSel,
    const float* __restrict__ attn, float* __restrict__ out)
{
    __shared__ float wl[4][L_ + 64];    // per-rank weights, j + 4*(j>>7) pad
    __shared__ float4 part[16][16];
    __shared__ int qr4[4];
    int b = blockIdx.x;
    int xcd = b & 7, s = b >> 3;          // s in 0..79
    int bh  = xcd + ((s / 10) << 3);
    int grp = s % 10;
    int t = threadIdx.x;
    if (t < 4) qr4[t] = idxSel[bh*NS + grp*4 + t];

    // stage 4 weight rows (coalesced f4 loads)
    #pragma unroll
    for (int it = 0; it < 8; ++it) {
        int f = t + 256*it;             // 0..2047 f4 across 4 rows
        int rr = f >> 9, fi = f & 511;
        const float4* ar = (const float4*)(attn + (size_t)(bh*NS + grp*4 + rr) * L_);
        float4 x = ar[fi];
        int j = 4*fi;
        *((float4*)&wl[rr][j + 4*(j >> 7)]) = x;
    }
    __syncthreads();

    int maxq = max(max(qr4[0], qr4[1]), max(qr4[2], qr4[3]));
    int d4 = t & 15, seg = t >> 4;
    const float4* vb = (const float4*)(v + (size_t)bh * L_ * D_);
    float4 acc[4];
    #pragma unroll
    for (int rr = 0; rr < 4; ++rr) acc[rr] = make_float4(0,0,0,0);

    int jlo = seg*128, jhi = min(jlo + 127, maxq);
    for (int j = jlo; j <= jhi; ++j) {
        float4 x = vb[(size_t)j*16 + d4];          // read once
        int jp = j + 4*(j >> 7);
        #pragma unroll
        for (int rr = 0; rr < 4; ++rr) {
            float wgt = wl[rr][jp];                // 2-way conflict (free)
            acc[rr].x += wgt*x.x; acc[rr].y += wgt*x.y;
            acc[rr].z += wgt*x.z; acc[rr].w += wgt*x.w;
        }
    }

    #pragma unroll
    for (int rr = 0; rr < 4; ++rr) {
        part[seg][d4] = acc[rr];
        __syncthreads();
        float4 a = acc[rr];
        for (int s2 = 8; s2; s2 >>= 1) {
            if (seg < s2) {
                float4 o = part[seg + s2][d4];
                a.x += o.x; a.y += o.y; a.z += o.z; a.w += o.w;
                part[seg][d4] = a;
            }
            __syncthreads();
        }
        if (seg == 0) {
            float4* orow = (float4*)(out + ((size_t)bh * L_ + qr4[rr]) * D_);
            orow[d4] = a;
        }
        __syncthreads();                // before part reuse
    }
}

// ---------------------------------------------------------------------------
extern "C" void kernel_launch(void* const* d_in, const int* in_sizes, int n_in,
                              void* d_out, int out_size, void* d_ws, size_t ws_size,
                              hipStream_t stream) {
    const float* q    = (const float*)d_in[0];
    const float* k    = (const float*)d_in[1];
    const float* v    = (const float*)d_in[2];
    const int*   ridx = (const int*)d_in[3];

    float* out     = (float*)d_out;                    // (B,H,L,D)
    float* attnOut = out + (size_t)BH * L_ * D_;       // (B,H,NS,L)

    float*  measure = (float*)d_ws;                                          // BH*L floats
    int*    idxSel  = (int*)((char*)d_ws + (size_t)BH * L_ * sizeof(float)); // BH*NS ints

    measure_cumsum_kernel<<<256 + BH * L_ / 4, 256, 0, stream>>>(
        q, k, ridx, measure, v, out);
    topk_kernel   <<<BH,          256, 0, stream>>>(measure, idxSel);
    scores_kernel <<<BH * 10,     256, 0, stream>>>(q, k, idxSel, attnOut);
    pv_kernel     <<<BH * 10,     256, 0, stream>>>(v, idxSel, attnOut, out);
}